// Round 15
// baseline (195.416 us; speedup 1.0000x reference)
//
#include <hip/hip_runtime.h>
#include <hip/hip_bf16.h>

// Shapes (fixed by the reference)
#define BB 16
#define HH 64
#define WW 64
#define CC 256
#define OH 128
#define OW 128
#define FF 256

typedef __attribute__((ext_vector_type(8))) short bf16x8;
typedef __attribute__((ext_vector_type(4))) float f32x4;

// RNE float -> bf16 bits
__device__ __forceinline__ short f2bf(float x) {
    union { float f; unsigned u; } v; v.f = x;
    unsigned r = v.u + 0x7fffu + ((v.u >> 16) & 1u);
    return (short)(r >> 16);
}

// packed f32x2 -> bf16x2 (1 VALU instr)
__device__ __forceinline__ unsigned cvtpk(float lo, float hi) {
    unsigned r;
    asm("v_cvt_pk_bf16_f32 %0, %1, %2" : "=v"(r) : "v"(lo), "v"(hi));
    return r;
}

// prep: blocks 0..31 build pwtF = pw in MFMA *fragment-linear* order:
//   entry e = ((wc*8 + kk)*4 + ni)*64 + lane   (bf16x8 per entry)
//   holds pw[c0..c0+7][f] with f = wc*64+ni*16+(lane&15), c0 = kk*32+(lane>>4)*8
// Block 32 repacks dw -> dwb [(r*256+c)*4+s] (f32).
__global__ void prep_kernel(const float* __restrict__ pw, const float* __restrict__ dw,
                            short* __restrict__ pwtF, float* __restrict__ dwb) {
    if (blockIdx.x < 32) {
        const int e    = blockIdx.x * 256 + threadIdx.x;
        const int lane = e & 63;
        const int ni   = (e >> 6) & 3;
        const int kk   = (e >> 8) & 7;
        const int wc   = e >> 11;
        const int f    = wc * 64 + ni * 16 + (lane & 15);
        const int c0   = kk * 32 + (lane >> 4) * 8;
        bf16x8 v;
        #pragma unroll
        for (int j = 0; j < 8; ++j) v[j] = f2bf(pw[(size_t)(c0 + j) * FF + f]);
        reinterpret_cast<bf16x8*>(pwtF)[e] = v;
    } else {
        for (int k = threadIdx.x; k < 4 * 4 * CC; k += 256) {
            int r = k >> 10;
            int rem = k & 1023;
            int s = rem >> 8;
            int c = rem & 255;
            dwb[(r * CC + c) * 4 + s] = dw[(r * 4 + s) * CC + c];
        }
    }
}

__device__ __forceinline__ void tap(float acc[8], const float w[8], const float* xptr) {
    const float4* xp = reinterpret_cast<const float4*>(xptr);
    float4 x0 = xp[0], x1 = xp[1];
    acc[0] += w[0] * x0.x; acc[1] += w[1] * x0.y;
    acc[2] += w[2] * x0.z; acc[3] += w[3] * x0.w;
    acc[4] += w[4] * x1.x; acc[5] += w[5] * x1.y;
    acc[6] += w[6] * x1.z; acc[7] += w[7] * x1.w;
}

// One block = one (b, oh) output row, processed as 4 quarters of 32 ow.
// Waves 0-3 = producers: depthwise (f32 taps from global) -> t_lds[q&1].
// Waves 4-7 = consumers: MFMA pointwise (fragment-linear B) + f32x4 stores.
// Plain __syncthreads() between quarters; PRODUCE(q+1) overlaps CONSUME(q).
// Compact XCD swizzle: XCD = blk%8 gets a contiguous slab of 256 (b,oh) rows,
// so the 4 rows sharing each X input row co-reside in one XCD's L2 (r8: FETCH 46MB).
__global__ __launch_bounds__(512, 4)
void sepconvt_kernel(const float* __restrict__ X,
                     const float* __restrict__ dwb,
                     const short* __restrict__ pwtF,
                     const float* __restrict__ bias,
                     float* __restrict__ out) {
    __shared__ bf16x8 t_lds[2][32 * 32];   // 2 x 16 KiB

    const int tid  = threadIdx.x;
    const int wid  = tid >> 6;
    const int lane = tid & 63;
    const bool producer = (wid < 4);
    const int work = ((blockIdx.x & 7) << 8) | (blockIdx.x >> 3);   // XCD-compact
    const int oh = work & (OH - 1);
    const int b  = work >> 7;

    // Row taps: even oh -> (r=1, i=oh/2), (r=3, i=oh/2-1); odd -> (r=0,(oh+1)/2),(r=2,(oh-1)/2)
    int r0, r1, i0, i1;
    if (oh & 1) { r0 = 0; i0 = (oh + 1) >> 1; r1 = 2; i1 = (oh - 1) >> 1; }
    else        { r0 = 1; i0 = oh >> 1;       r1 = 3; i1 = (oh >> 1) - 1; }

    if (producer) {
        // -------- producer persona (tid 0..255): depthwise into t_lds --------
        const int cg  = tid & 31;         // 8-channel group
        const int c0  = cg << 3;
        const int owp = (tid >> 5) & 7;   // 0..7, ow stride 8
        const int par = owp & 1;

        float w[2][2][8];
        const float4* dwb4 = reinterpret_cast<const float4*>(dwb);
        #pragma unroll
        for (int e = 0; e < 8; ++e) {
            float4 wa = dwb4[r0 * CC + c0 + e];
            float4 wb = dwb4[r1 * CC + c0 + e];
            w[0][0][e] = par ? wa.x : wa.y;
            w[0][1][e] = par ? wa.z : wa.w;
            w[1][0][e] = par ? wb.x : wb.y;
            w[1][1][e] = par ? wb.z : wb.w;
        }

        const bool va0 = (unsigned)i0 < HH;
        const bool va1 = (unsigned)i1 < HH;
        const float* Xr0 = X + (size_t)(b * HH + (va0 ? i0 : 0)) * WW * CC;
        const float* Xr1 = X + (size_t)(b * HH + (va1 ? i1 : 0)) * WW * CC;

        #pragma unroll
        for (int q = 0; q < 4; ++q) {
            const int qb = q & 1;
            #pragma unroll
            for (int h = 0; h < 4; ++h) {
                const int owl = owp + h * 8;      // 0..31
                const int ow  = q * 32 + owl;
                int je, jo;
                if (par) { je = (ow + 1) >> 1; jo = (ow - 1) >> 1; }
                else     { je = ow >> 1;       jo = (ow >> 1) - 1; }
                const bool vje = (unsigned)je < WW;
                const bool vjo = (unsigned)jo < WW;

                float acc[8];
                #pragma unroll
                for (int e = 0; e < 8; ++e) acc[e] = 0.f;

                if (va0) {
                    if (vje) tap(acc, w[0][0], Xr0 + je * CC + c0);
                    if (vjo) tap(acc, w[0][1], Xr0 + jo * CC + c0);
                }
                if (va1) {
                    if (vje) tap(acc, w[1][0], Xr1 + je * CC + c0);
                    if (vjo) tap(acc, w[1][1], Xr1 + jo * CC + c0);
                }

                union { unsigned u[4]; bf16x8 v; } pk;
                pk.u[0] = cvtpk(acc[0], acc[1]);
                pk.u[1] = cvtpk(acc[2], acc[3]);
                pk.u[2] = cvtpk(acc[4], acc[5]);
                pk.u[3] = cvtpk(acc[6], acc[7]);
                t_lds[qb][owl * 32 + (cg ^ (owl & 7))] = pk.v;
            }
            __syncthreads();                       // tile q ready
        }
    } else {
        // -------- consumer persona (tid 256..511): MFMA + epilogue --------
        const int wc  = wid - 4;          // 0..3 -> f block
        const int lr  = lane & 15;
        const int lk8 = lane >> 4;
        const bf16x8* pvF = reinterpret_cast<const bf16x8*>(pwtF) + (size_t)wc * 2048 + lane;

        f32x4 bv[4];
        #pragma unroll
        for (int ni = 0; ni < 4; ++ni)
            bv[ni] = *reinterpret_cast<const f32x4*>(&bias[wc * 64 + ni * 16 + lk8 * 4]);

        #pragma unroll
        for (int q = 0; q < 4; ++q) {
            __syncthreads();                       // wait tile q
            const int qb = q & 1;

            f32x4 acc[2][4];
            #pragma unroll
            for (int mi = 0; mi < 2; ++mi)
                #pragma unroll
                for (int ni = 0; ni < 4; ++ni)
                    acc[mi][ni] = (f32x4){0.f, 0.f, 0.f, 0.f};

            #pragma unroll
            for (int kk = 0; kk < 8; ++kk) {
                const int kg = kk * 4 + lk8;
                bf16x8 af[2], bfr[4];
                #pragma unroll
                for (int mi = 0; mi < 2; ++mi) {
                    const int row = mi * 16 + lr;
                    af[mi] = t_lds[qb][row * 32 + (kg ^ (row & 7))];
                }
                #pragma unroll
                for (int ni = 0; ni < 4; ++ni)
                    bfr[ni] = pvF[(kk * 4 + ni) * 64];   // dense 1KB wave burst
                #pragma unroll
                for (int mi = 0; mi < 2; ++mi)
                    #pragma unroll
                    for (int ni = 0; ni < 4; ++ni)
                        acc[mi][ni] = __builtin_amdgcn_mfma_f32_16x16x32_bf16(
                            bfr[ni], af[mi], acc[mi][ni], 0, 0, 0);
            }

            float* obase = out + ((size_t)(b * OH + oh) * OW + q * 32) * FF;
            #pragma unroll
            for (int ni = 0; ni < 4; ++ni) {
                const int f0 = wc * 64 + ni * 16 + lk8 * 4;
                #pragma unroll
                for (int mi = 0; mi < 2; ++mi) {
                    const int ow = mi * 16 + lr;
                    f32x4 v = acc[mi][ni] + bv[ni];
                    v[0] = v[0] > 0.f ? v[0] : 0.f;
                    v[1] = v[1] > 0.f ? v[1] : 0.f;
                    v[2] = v[2] > 0.f ? v[2] : 0.f;
                    v[3] = v[3] > 0.f ? v[3] : 0.f;
                    *reinterpret_cast<f32x4*>(&obase[(size_t)ow * FF + f0]) = v;
                }
            }
        }
    }
}

extern "C" void kernel_launch(void* const* d_in, const int* in_sizes, int n_in,
                              void* d_out, int out_size, void* d_ws, size_t ws_size,
                              hipStream_t stream) {
    (void)in_sizes; (void)n_in; (void)out_size; (void)ws_size;
    const float* X    = (const float*)d_in[0];
    const float* dw   = (const float*)d_in[1];
    const float* pw   = (const float*)d_in[2];
    const float* bias = (const float*)d_in[3];
    float* out = (float*)d_out;
    short* pwtF = (short*)d_ws;                       // 8192 entries * 16B = 128 KiB
    float* dwb  = (float*)((char*)d_ws + 131072);     // 16 KiB

    prep_kernel<<<dim3(33), dim3(256), 0, stream>>>(pw, dw, pwtF, dwb);
    sepconvt_kernel<<<dim3(BB * OH), dim3(512), 0, stream>>>(X, dwb, pwtF, bias, out);
}

// Round 16
// 148.486 us; speedup vs baseline: 1.3161x; 1.3161x over previous
//
#include <hip/hip_runtime.h>
#include <hip/hip_bf16.h>

// Shapes (fixed by the reference)
#define BB 16
#define HH 64
#define WW 64
#define CC 256
#define OH 128
#define OW 128
#define FF 256

typedef __attribute__((ext_vector_type(8))) short bf16x8;
typedef __attribute__((ext_vector_type(4))) float f32x4;

// RNE float -> bf16 bits
__device__ __forceinline__ short f2bf(float x) {
    union { float f; unsigned u; } v; v.f = x;
    unsigned r = v.u + 0x7fffu + ((v.u >> 16) & 1u);
    return (short)(r >> 16);
}

// packed f32x2 -> bf16x2 (1 VALU instr)
__device__ __forceinline__ unsigned cvtpk(float lo, float hi) {
    unsigned r;
    asm("v_cvt_pk_bf16_f32 %0, %1, %2" : "=v"(r) : "v"(lo), "v"(hi));
    return r;
}

// prep: blocks 0..31 build pwtF = pw in MFMA *fragment-linear* order:
//   entry e = ((wc*8 + kk)*4 + ni)*64 + lane   (bf16x8 per entry)
//   holds pw[c0..c0+7][f] with f = wc*64+ni*16+(lane&15), c0 = kk*32+(lane>>4)*8
// Block 32 repacks dw -> dwb [(r*256+c)*4+s] (f32).
__global__ void prep_kernel(const float* __restrict__ pw, const float* __restrict__ dw,
                            short* __restrict__ pwtF, float* __restrict__ dwb) {
    if (blockIdx.x < 32) {
        const int e    = blockIdx.x * 256 + threadIdx.x;
        const int lane = e & 63;
        const int ni   = (e >> 6) & 3;
        const int kk   = (e >> 8) & 7;
        const int wc   = e >> 11;
        const int f    = wc * 64 + ni * 16 + (lane & 15);
        const int c0   = kk * 32 + (lane >> 4) * 8;
        bf16x8 v;
        #pragma unroll
        for (int j = 0; j < 8; ++j) v[j] = f2bf(pw[(size_t)(c0 + j) * FF + f]);
        reinterpret_cast<bf16x8*>(pwtF)[e] = v;
    } else {
        for (int k = threadIdx.x; k < 4 * 4 * CC; k += 256) {
            int r = k >> 10;
            int rem = k & 1023;
            int s = rem >> 8;
            int c = rem & 255;
            dwb[(r * CC + c) * 4 + s] = dw[(r * 4 + s) * CC + c];
        }
    }
}

// One block = one (b, oh) output row, processed as 4 quarters of 32 ow.
// Waves 0-3 = producers: sliding-window depthwise (5 col loads per 4 outputs)
//   -> t_lds[q&1]. Waves 4-7 = consumers: MFMA pointwise + f32x4 stores.
// Plain __syncthreads() between quarters; PRODUCE(q+1) overlaps CONSUME(q).
__global__ __launch_bounds__(512, 4)
void sepconvt_kernel(const float* __restrict__ X,
                     const float* __restrict__ dwb,
                     const short* __restrict__ pwtF,
                     const float* __restrict__ bias,
                     float* __restrict__ out) {
    __shared__ bf16x8 t_lds[2][32 * 32];   // 2 x 16 KiB

    const int tid  = threadIdx.x;
    const int wid  = tid >> 6;
    const int lane = tid & 63;
    const bool producer = (wid < 4);
    const int blk  = blockIdx.x;          // b*OH + oh
    const int oh = blk & (OH - 1);
    const int b  = blk >> 7;

    // Row taps: even oh -> (r=1, i=oh/2), (r=3, i=oh/2-1); odd -> (r=0,(oh+1)/2),(r=2,(oh-1)/2)
    int r0, r1, i0, i1;
    if (oh & 1) { r0 = 0; i0 = (oh + 1) >> 1; r1 = 2; i1 = (oh - 1) >> 1; }
    else        { r0 = 1; i0 = oh >> 1;       r1 = 3; i1 = (oh >> 1) - 1; }

    if (producer) {
        // -------- producer persona (tid 0..255): streaming depthwise --------
        const int cg  = tid & 31;         // 8-channel group
        const int c0  = cg << 3;
        const int owp = (tid >> 5) & 7;
        const int p   = owp & 1;          // ow parity
        const int seg = owp >> 1;         // 0..3: contiguous run of 4 same-parity ow

        const bool va0 = (unsigned)i0 < HH;
        const bool va1 = (unsigned)i1 < HH;

        // w[row][0] = je-weight (s = p?0:1), w[row][1] = jo-weight (s = p?2:3);
        // invalid rows zeroed (keeps the stream branch-free).
        float w[2][2][8];
        const float4* dwb4 = reinterpret_cast<const float4*>(dwb);
        #pragma unroll
        for (int e = 0; e < 8; ++e) {
            float4 wa = dwb4[r0 * CC + c0 + e];
            float4 wb = dwb4[r1 * CC + c0 + e];
            w[0][0][e] = va0 ? (p ? wa.x : wa.y) : 0.f;
            w[0][1][e] = va0 ? (p ? wa.z : wa.w) : 0.f;
            w[1][0][e] = va1 ? (p ? wb.x : wb.y) : 0.f;
            w[1][1][e] = va1 ? (p ? wb.z : wb.w) : 0.f;
        }

        const float* Xr0 = X + (size_t)(b * HH + (va0 ? i0 : 0)) * WW * CC;
        const float* Xr1 = X + (size_t)(b * HH + (va1 ? i1 : 0)) * WW * CC;

        #pragma unroll
        for (int q = 0; q < 4; ++q) {
            const int qb = q & 1;
            // thread outputs: owl = seg*8 + p + 2k (k=0..3); je(ow_0) = q*16+seg*4+p
            const int j0 = q * 16 + seg * 4 + p;

            // xPrev = column j0-1 (jo-tap of k=0); invalid only when j0==0 (q=0)
            float xp0[8], xp1[8];
            {
                const int cm1 = (j0 > 0) ? (j0 - 1) : 0;
                const float4* a0 = reinterpret_cast<const float4*>(Xr0 + cm1 * CC + c0);
                const float4* a1 = reinterpret_cast<const float4*>(Xr1 + cm1 * CC + c0);
                float4 u0 = a0[0], u1 = a0[1], v0 = a1[0], v1 = a1[1];
                if (q == 0 && j0 == 0) {
                    u0 = u1 = v0 = v1 = (float4){0.f, 0.f, 0.f, 0.f};
                }
                xp0[0]=u0.x; xp0[1]=u0.y; xp0[2]=u0.z; xp0[3]=u0.w;
                xp0[4]=u1.x; xp0[5]=u1.y; xp0[6]=u1.z; xp0[7]=u1.w;
                xp1[0]=v0.x; xp1[1]=v0.y; xp1[2]=v0.z; xp1[3]=v0.w;
                xp1[4]=v1.x; xp1[5]=v1.y; xp1[6]=v1.z; xp1[7]=v1.w;
            }

            #pragma unroll
            for (int k = 0; k < 4; ++k) {
                const int jc = j0 + k;                 // je column of output k
                const int jcc = (jc < WW) ? jc : (WW - 1);
                const float4* a0 = reinterpret_cast<const float4*>(Xr0 + jcc * CC + c0);
                const float4* a1 = reinterpret_cast<const float4*>(Xr1 + jcc * CC + c0);
                float4 u0 = a0[0], u1 = a0[1], v0 = a1[0], v1 = a1[1];
                if (k == 3 && q == 3 && jc >= WW) {    // only ow=127's je (col 64)
                    u0 = u1 = v0 = v1 = (float4){0.f, 0.f, 0.f, 0.f};
                }
                float xc0[8], xc1[8];
                xc0[0]=u0.x; xc0[1]=u0.y; xc0[2]=u0.z; xc0[3]=u0.w;
                xc0[4]=u1.x; xc0[5]=u1.y; xc0[6]=u1.z; xc0[7]=u1.w;
                xc1[0]=v0.x; xc1[1]=v0.y; xc1[2]=v0.z; xc1[3]=v0.w;
                xc1[4]=v1.x; xc1[5]=v1.y; xc1[6]=v1.z; xc1[7]=v1.w;

                float acc[8];
                #pragma unroll
                for (int e = 0; e < 8; ++e)
                    acc[e] = w[0][0][e] * xc0[e] + w[0][1][e] * xp0[e]
                           + w[1][0][e] * xc1[e] + w[1][1][e] * xp1[e];

                union { unsigned u[4]; bf16x8 v; } pk;
                pk.u[0] = cvtpk(acc[0], acc[1]);
                pk.u[1] = cvtpk(acc[2], acc[3]);
                pk.u[2] = cvtpk(acc[4], acc[5]);
                pk.u[3] = cvtpk(acc[6], acc[7]);
                const int owl = seg * 8 + p + 2 * k;   // 0..31
                t_lds[qb][owl * 32 + (cg ^ (owl & 7))] = pk.v;

                #pragma unroll
                for (int e = 0; e < 8; ++e) { xp0[e] = xc0[e]; xp1[e] = xc1[e]; }
            }
            __syncthreads();                       // tile q ready
        }
    } else {
        // -------- consumer persona (tid 256..511): MFMA + epilogue --------
        const int wc  = wid - 4;          // 0..3 -> f block
        const int lr  = lane & 15;
        const int lk8 = lane >> 4;
        const bf16x8* pvF = reinterpret_cast<const bf16x8*>(pwtF) + (size_t)wc * 2048 + lane;

        f32x4 bv[4];
        #pragma unroll
        for (int ni = 0; ni < 4; ++ni)
            bv[ni] = *reinterpret_cast<const f32x4*>(&bias[wc * 64 + ni * 16 + lk8 * 4]);

        #pragma unroll
        for (int q = 0; q < 4; ++q) {
            __syncthreads();                       // wait tile q
            const int qb = q & 1;

            f32x4 acc[2][4];
            #pragma unroll
            for (int mi = 0; mi < 2; ++mi)
                #pragma unroll
                for (int ni = 0; ni < 4; ++ni)
                    acc[mi][ni] = (f32x4){0.f, 0.f, 0.f, 0.f};

            #pragma unroll
            for (int kk = 0; kk < 8; ++kk) {
                const int kg = kk * 4 + lk8;
                bf16x8 af[2], bfr[4];
                #pragma unroll
                for (int mi = 0; mi < 2; ++mi) {
                    const int row = mi * 16 + lr;
                    af[mi] = t_lds[qb][row * 32 + (kg ^ (row & 7))];
                }
                #pragma unroll
                for (int ni = 0; ni < 4; ++ni)
                    bfr[ni] = pvF[(kk * 4 + ni) * 64];   // dense 1KB wave burst
                #pragma unroll
                for (int mi = 0; mi < 2; ++mi)
                    #pragma unroll
                    for (int ni = 0; ni < 4; ++ni)
                        acc[mi][ni] = __builtin_amdgcn_mfma_f32_16x16x32_bf16(
                            bfr[ni], af[mi], acc[mi][ni], 0, 0, 0);
            }

            float* obase = out + ((size_t)(b * OH + oh) * OW + q * 32) * FF;
            #pragma unroll
            for (int ni = 0; ni < 4; ++ni) {
                const int f0 = wc * 64 + ni * 16 + lk8 * 4;
                #pragma unroll
                for (int mi = 0; mi < 2; ++mi) {
                    const int ow = mi * 16 + lr;
                    f32x4 v = acc[mi][ni] + bv[ni];
                    v[0] = v[0] > 0.f ? v[0] : 0.f;
                    v[1] = v[1] > 0.f ? v[1] : 0.f;
                    v[2] = v[2] > 0.f ? v[2] : 0.f;
                    v[3] = v[3] > 0.f ? v[3] : 0.f;
                    *reinterpret_cast<f32x4*>(&obase[(size_t)ow * FF + f0]) = v;
                }
            }
        }
    }
}

extern "C" void kernel_launch(void* const* d_in, const int* in_sizes, int n_in,
                              void* d_out, int out_size, void* d_ws, size_t ws_size,
                              hipStream_t stream) {
    (void)in_sizes; (void)n_in; (void)out_size; (void)ws_size;
    const float* X    = (const float*)d_in[0];
    const float* dw   = (const float*)d_in[1];
    const float* pw   = (const float*)d_in[2];
    const float* bias = (const float*)d_in[3];
    float* out = (float*)d_out;
    short* pwtF = (short*)d_ws;                       // 8192 entries * 16B = 128 KiB
    float* dwb  = (float*)((char*)d_ws + 131072);     // 16 KiB

    prep_kernel<<<dim3(33), dim3(256), 0, stream>>>(pw, dw, pwtF, dwb);
    sepconvt_kernel<<<dim3(BB * OH), dim3(512), 0, stream>>>(X, dwb, pwtF, bias, out);
}